// Round 1
// baseline (873.669 us; speedup 1.0000x reference)
//
#include <hip/hip_runtime.h>

#define Hh 51
#define HP 52      // H padded to multiple of 4
#define TT 512     // time steps
#define BT 512     // threads per block (8 waves)
#define NB 256     // blocks (2 batch rows each -> 512 rows)

#define LOG2E 1.4426950408889634f

__device__ __forceinline__ float fexp2(float x) { return __builtin_amdgcn_exp2f(x); }
__device__ __forceinline__ float frcp(float x)  { return __builtin_amdgcn_rcpf(x); }
__device__ __forceinline__ float sigm(float x)  { return frcp(1.f + fexp2(-LOG2E * x)); }
__device__ __forceinline__ float ftanh(float x) { return 1.f - 2.f * frcp(1.f + fexp2(2.f * LOG2E * x)); }

__global__ __launch_bounds__(BT, 2) void lstm2_persistent(
    const float* __restrict__ input,   // [512,512]
    const float* __restrict__ W_ih1,   // [204] (4H x 1)
    const float* __restrict__ W_hh1,   // [204,51]
    const float* __restrict__ b_ih1,   // [204]
    const float* __restrict__ b_hh1,   // [204]
    const float* __restrict__ W_ih2,   // [204,51]
    const float* __restrict__ W_hh2,   // [204,51]
    const float* __restrict__ b_ih2,   // [204]
    const float* __restrict__ b_hh2,   // [204]
    const float* __restrict__ W_lin,   // [51]
    const float* __restrict__ b_lin,   // [1]
    float* __restrict__ out)           // [512,512]
{
    __shared__ float xbuf[2][TT];                       // 4 KB: input time series, 2 rows
    __shared__ __align__(16) float h1buf[2][HP];
    __shared__ __align__(16) float h2buf[2][HP];
    __shared__ float z1buf[2][256];
    __shared__ float z2buf[2][256];

    const int tid = threadIdx.x;
    const int row = tid >> 8;          // 0..1 (local batch row)
    const int j   = tid & 255;         // gate-row index, active < 204
    const bool act = (j < 4 * Hh);
    const bool upd = (j < Hh);         // lanes doing the gate/state update
    const int grow = (blockIdx.x << 1) + row;

    // preload the 2 input rows into LDS (coalesced: rows are contiguous)
    {
        int idx0 = tid;                // covers [0,512)
        int idx1 = tid + BT;           // covers [512,1024)
        xbuf[0][idx0 & 511] = input[((blockIdx.x << 1) + 0) * TT + (idx0 & 511)];
        xbuf[1][idx1 & 511] = input[((blockIdx.x << 1) + 1) * TT + (idx1 & 511)];
    }
    if (tid < 2 * HP) { ((float*)h1buf)[tid] = 0.f; ((float*)h2buf)[tid] = 0.f; }

    // ---- persistent weights in registers: 3 x 52 floats per lane ----
    float wh1[HP], wi2[HP], wh2[HP];
    float wih1 = 0.f, bb1 = 0.f, bb2 = 0.f, wlin = 0.f;
    if (act) {
#pragma unroll
        for (int k = 0; k < Hh; ++k) {
            wh1[k] = W_hh1[j * Hh + k];
            wi2[k] = W_ih2[j * Hh + k];
            wh2[k] = W_hh2[j * Hh + k];
        }
        wh1[Hh] = 0.f; wi2[Hh] = 0.f; wh2[Hh] = 0.f;
        wih1 = W_ih1[j];
        bb1  = b_ih1[j] + b_hh1[j];
        bb2  = b_ih2[j] + b_hh2[j];
    } else {
#pragma unroll
        for (int k = 0; k < HP; ++k) { wh1[k] = 0.f; wi2[k] = 0.f; wh2[k] = 0.f; }
    }
    if (upd) wlin = W_lin[j];
    const float blin = b_lin[0];
    float c1 = 0.f, c2 = 0.f;          // cell state lives in update-lane registers

    __syncthreads();

    const float4* h1v = (const float4*)(&h1buf[row][0]);   // row offset 208 B: 16-aligned
    const float4* h2v = (const float4*)(&h2buf[row][0]);

    for (int t = 0; t < TT; ++t) {
        // ---- phase 1: z1 = b1 + x*W_ih1 + W_hh1.h1_old ; z2_partial = b2 + W_hh2.h2_old
        float x  = xbuf[row][t];
        float a1 = fmaf(x, wih1, bb1);
        float a2 = bb2;
#pragma unroll
        for (int c = 0; c < HP / 4; ++c) {
            float4 hv = h1v[c];
            float4 gv = h2v[c];
            a1 = fmaf(wh1[4 * c + 0], hv.x, a1);
            a1 = fmaf(wh1[4 * c + 1], hv.y, a1);
            a1 = fmaf(wh1[4 * c + 2], hv.z, a1);
            a1 = fmaf(wh1[4 * c + 3], hv.w, a1);
            a2 = fmaf(wh2[4 * c + 0], gv.x, a2);
            a2 = fmaf(wh2[4 * c + 1], gv.y, a2);
            a2 = fmaf(wh2[4 * c + 2], gv.z, a2);
            a2 = fmaf(wh2[4 * c + 3], gv.w, a2);
        }
        z1buf[row][j] = a1;
        __syncthreads();                                   // A

        // ---- phase 2: layer-1 gate update (lanes j<51), h1_new -> LDS
        if (upd) {
            float zi = z1buf[row][j];
            float zf = z1buf[row][j + Hh];
            float zg = z1buf[row][j + 2 * Hh];
            float zo = z1buf[row][j + 3 * Hh];
            float ii = sigm(zi), ff = sigm(zf), gg = ftanh(zg), oo = sigm(zo);
            c1 = fmaf(ff, c1, ii * gg);
            h1buf[row][j] = oo * ftanh(c1);
        }
        __syncthreads();                                   // B

        // ---- phase 3: z2 += W_ih2.h1_new
#pragma unroll
        for (int c = 0; c < HP / 4; ++c) {
            float4 hv = h1v[c];
            a2 = fmaf(wi2[4 * c + 0], hv.x, a2);
            a2 = fmaf(wi2[4 * c + 1], hv.y, a2);
            a2 = fmaf(wi2[4 * c + 2], hv.z, a2);
            a2 = fmaf(wi2[4 * c + 3], hv.w, a2);
        }
        z2buf[row][j] = a2;
        __syncthreads();                                   // C

        // ---- phase 4: layer-2 gate update + linear output
        float p = 0.f;
        if (upd) {
            float zi = z2buf[row][j];
            float zf = z2buf[row][j + Hh];
            float zg = z2buf[row][j + 2 * Hh];
            float zo = z2buf[row][j + 3 * Hh];
            float ii = sigm(zi), ff = sigm(zf), gg = ftanh(zg), oo = sigm(zo);
            c2 = fmaf(ff, c2, ii * gg);
            float h2n = oo * ftanh(c2);
            h2buf[row][j] = h2n;
            p = wlin * h2n;
        }
        if ((j >> 6) == 0) {           // wave-uniform: only the wave holding lanes j<64
#pragma unroll
            for (int off = 32; off >= 1; off >>= 1)
                p += __shfl_xor(p, off, 64);
            if (j == 0) out[grow * TT + t] = p + blin;
        }
        __syncthreads();                                   // D (protects h1/h2/z re-use)
    }
}

extern "C" void kernel_launch(void* const* d_in, const int* in_sizes, int n_in,
                              void* d_out, int out_size, void* d_ws, size_t ws_size,
                              hipStream_t stream) {
    const float* input = (const float*)d_in[0];
    const float* W_ih1 = (const float*)d_in[1];
    const float* W_hh1 = (const float*)d_in[2];
    const float* b_ih1 = (const float*)d_in[3];
    const float* b_hh1 = (const float*)d_in[4];
    const float* W_ih2 = (const float*)d_in[5];
    const float* W_hh2 = (const float*)d_in[6];
    const float* b_ih2 = (const float*)d_in[7];
    const float* b_hh2 = (const float*)d_in[8];
    const float* W_lin = (const float*)d_in[9];
    const float* b_lin = (const float*)d_in[10];
    // d_in[11] = future (0 in this benchmark) -- ignored
    float* out = (float*)d_out;

    hipLaunchKernelGGL(lstm2_persistent, dim3(NB), dim3(BT), 0, stream,
                       input, W_ih1, W_hh1, b_ih1, b_hh1,
                       W_ih2, W_hh2, b_ih2, b_hh2, W_lin, b_lin, out);
}